// Round 12
// baseline (236.475 us; speedup 1.0000x reference)
//
#include <hip/hip_runtime.h>
#include <hip/hip_bf16.h>
#include <cmath>

// ---------------------------------------------------------------------------
// NPerTokenSwishGLU_Basis — fused f16-MFMA implementation (gfx950), round 19.
//
// R18 post-mortem: byte-model dead (P -128MB -> 0 time change; re-reads are
// L2-resident, HBM FETCH only ~25MB). 12-round elimination leaves ONE never-
// varied knob: iteration count. Measured ~3.1us (~7500cy) per barrier-locked
// iteration vs ~1500cy of identifiable work -> fixed per-iteration cost.
// R19: BK 32->64 — up 16->8 iters, down 8->4 iters, double per-iter work,
// R14 geometry otherwise. Wt per-l stride 1096 (pad 8, dw stride == 4 mod 32,
// bank-identical to proven 584). LDS 71.2KB -> 2 blocks/CU.
// __launch_bounds__(256,2) for the 128-VGPR grant (demand ~115).
// ---------------------------------------------------------------------------

typedef _Float16 half8 __attribute__((ext_vector_type(8)));
typedef _Float16 half4 __attribute__((ext_vector_type(4)));
typedef float    f32x4 __attribute__((ext_vector_type(4)));
typedef float    f32x2 __attribute__((ext_vector_type(2)));

#define MFMA_F16  __builtin_amdgcn_mfma_f32_16x16x32_f16
#define MFMA16    __builtin_amdgcn_mfma_f32_16x16x16f16

// LDS-only barrier: drain DS ops, leave global loads in flight.
#define LDS_BARRIER()                                           \
    do {                                                        \
        asm volatile("s_waitcnt lgkmcnt(0)" ::: "memory");      \
        __builtin_amdgcn_s_barrier();                           \
    } while (0)

static constexpr size_t OFF_P1  = 0;            // 16 MiB; Rp overlay (down)
static constexpr size_t OFF_P2  = 16777216;     // 16 MiB; Np overlay (down, 1 MiB)
static constexpr size_t OFF_P3n = 17825792;     // 16 MiB at 17 MiB (after Np)
static constexpr size_t OFF_XA  = 33554432;     // 2 MiB at 32 MiB
static constexpr size_t OFF_U2  = 35651584;     // 4 MiB at 34 MiB
static constexpr size_t OFF_S   = 39845888;     // 4 MiB at 38 MiB (top 42 MiB)
static constexpr size_t WS_FAST = 54525952;     // 52 MiB (proven)

// ---------------------------------------------------------------------------
// prep (two-sided coalesced transpose), 32x32 tiles (R13):
//   z=0,1: wg/wu (K,512,1024)=[k][d][f] -> P[f][d][k]
//   z=2  : wd    (K,1024,512)=[k][f][d] -> P3[d][f][k]
// ---------------------------------------------------------------------------
__global__ __launch_bounds__(256) void prep_basis_all(
    const float* __restrict__ wg, const float* __restrict__ wu,
    const float* __restrict__ wd,
    _Float16* __restrict__ P1, _Float16* __restrict__ P2,
    _Float16* __restrict__ P3, int zoff)
{
    int z = blockIdx.y + zoff;
    const float* src = (z == 0) ? wg : (z == 1) ? wu : wd;
    _Float16*    dst = (z == 0) ? P1 : (z == 1) ? P2 : P3;
    int Amin = (z == 2) ? 1024 : 512;    // minor-dim size
    int Bmaj = (z == 2) ? 512 : 1024;    // major-dim size
    int nM = Bmaj >> 5;
    int m0 = (blockIdx.x / nM) * 32;     // minor base
    int M0 = (blockIdx.x % nM) * 32;     // major base

    __shared__ float S[16 * 1088];       // [k][row*34 + col]
    int t = threadIdx.x;

    int row = t >> 3;                    // 0..31 (minor row)
    int cg  = t & 7;                     // 0..7 (16B col group)
#pragma unroll
    for (int k = 0; k < 16; ++k) {
        f32x4 v = *(const f32x4*)(
            src + (size_t)k * Amin * Bmaj + (size_t)(m0 + row) * Bmaj + M0 + cg * 4);
        f32x2 lo = { v[0], v[1] };
        f32x2 hi = { v[2], v[3] };
        *(f32x2*)(&S[k * 1088 + row * 34 + cg * 4])     = lo;
        *(f32x2*)(&S[k * 1088 + row * 34 + cg * 4 + 2]) = hi;
    }
    __syncthreads();

    int mn = t & 31, mjq = t >> 5;
#pragma unroll
    for (int q = 0; q < 4; ++q) {
        int mj = q * 8 + mjq;
        half8 v0, v1;
#pragma unroll
        for (int k = 0; k < 8; ++k) v0[k] = (_Float16)S[k * 1088 + mn * 34 + mj];
#pragma unroll
        for (int k = 0; k < 8; ++k) v1[k] = (_Float16)S[(k + 8) * 1088 + mn * 34 + mj];
        _Float16* out = dst + ((size_t)(M0 + mj) * Amin + m0 + mn) * 16;
        *(half8*)out       = v0;
        *(half8*)(out + 8) = v1;
    }
}

// ---------------------------------------------------------------------------
// prep_x: x fp32 [b][l][d] -> XA f16 [l][d>>3][b][8]
// grid 256 = 128 l x 2 b-halves, 256 threads.
// ---------------------------------------------------------------------------
__global__ __launch_bounds__(256) void prep_x(
    const float* __restrict__ x, _Float16* __restrict__ XA)
{
    int l = blockIdx.x >> 1, bh = blockIdx.x & 1;
    __shared__ __align__(16) _Float16 XT[8][524];
    int t = threadIdx.x;

    int bl = t >> 5, q = t & 31;          // b-local 0..7, q 0..31
    int b = bh * 8 + bl;
#pragma unroll
    for (int j = 0; j < 4; ++j) {
        f32x4 v = *(const f32x4*)(x + ((size_t)(b * 128 + l) * 512 + j * 128 + q * 4));
#pragma unroll
        for (int i = 0; i < 4; ++i)
            XT[bl][j * 128 + q * 4 + i] = (_Float16)v[i];
    }
    __syncthreads();

    int c = t >> 2, bi = t & 3;           // c 0..63
#pragma unroll
    for (int s = 0; s < 2; ++s) {
        int blw = bi * 2 + s;             // 0..7
        half8 h = *(const half8*)(&XT[blw][c * 8]);
        *(half8*)(XA + (((size_t)(l * 64 + c) * 16 + bh * 8 + blw) * 8)) = h;
    }
}

// ---------------------------------------------------------------------------
// up_split (R19): 1024 blocks = mh(2) x 8 lg x 64 f-tiles, 256 thr.
// BK=64: 8 iterations of 64-d chunks. Mix fl(4)xdg(4) K=16 MFMA; consume
// li(4)x2 d-subs. Wt per-l stride 1096 (pad 8). LDS 71.2KB -> 2 blocks/CU.
// ---------------------------------------------------------------------------
__global__ __launch_bounds__(256, 2) void up_split(
    const _Float16* __restrict__ P1, const _Float16* __restrict__ P2,
    const _Float16* __restrict__ XA,
    const float* __restrict__ tc1, const float* __restrict__ tc2,
    const float* __restrict__ usp, const float* __restrict__ vsp,
    _Float16* __restrict__ U2, _Float16* __restrict__ S)
{
    int bid = blockIdx.x;
    int mh = bid >> 9;                  // 0: gate/u, 1: up/v
    int lg = (bid >> 6) & 7;
    int f0 = (bid & 63) * 16;
    int tid = threadIdx.x;
    int w = tid >> 6, lane = tid & 63;
    int n = lane & 15, kc = lane >> 4;

    const _Float16* P  = mh ? P2 : P1;
    const float*    tc = mh ? tc2 : tc1;

    __shared__ __align__(16) _Float16 Wt[2][16 * 1096]; // [buf][l*1096+f*68+d64]
    __shared__ float CN[256];

    // element-unit base pointers (advance +1024 per 64-d chunk)
    const _Float16* pP  = P + ((size_t)(f0 + w * 4) * 512 + n) * 16 + kc * 4;
    const _Float16* pXA = XA + (((size_t)(lg * 16 + w * 4) * 64 + kc) * 16 + n) * 8;

    half4 pa[4][4];
    // ---- prologue: issue pa(0) (d 0..63); softmax+barrier cover latency ----
#pragma unroll
    for (int fl = 0; fl < 4; ++fl)
#pragma unroll
        for (int dg = 0; dg < 4; ++dg)
            pa[fl][dg] = *(const half4*)(pP + fl * 8192 + dg * 256);
    const _Float16* qP = pP + 1024;

    if (tid < 16) {
        const float* row = tc + (size_t)(lg * 16 + tid) * 16;
        float e[16], m = -1e30f, sum = 0.f;
#pragma unroll
        for (int k = 0; k < 16; ++k) m = fmaxf(m, row[k]);
#pragma unroll
        for (int k = 0; k < 16; ++k) { e[k] = __expf(row[k] - m); sum += e[k]; }
        float r = 1.f / sum;
#pragma unroll
        for (int k = 0; k < 16; ++k) CN[tid * 16 + k] = e[k] * r;
    }
    __syncthreads();

    half4 cf;
#pragma unroll
    for (int j = 0; j < 4; ++j)
        cf[j] = (_Float16)CN[n * 16 + kc * 4 + j];

    f32x4 zf = { 0.f, 0.f, 0.f, 0.f };
    f32x4 aU[4];
#pragma unroll
    for (int i = 0; i < 4; ++i) aU[i] = zf;
    float nsq[4] = { 0.f, 0.f, 0.f, 0.f };
    half8 xfa[4], xfb[4];

#pragma unroll 1
    for (int it = 0; it < 8; ++it) {
        _Float16* WtW = &Wt[it & 1][0];
        const _Float16* WtR = &Wt[(it & 1) ^ 1][0];

        // ---- mix(it): 16 K=16 MFMAs over d 0..63 ----
#pragma unroll
        for (int fl = 0; fl < 4; ++fl) {
            int f_l = w * 4 + fl;
#pragma unroll
            for (int dg = 0; dg < 4; ++dg) {
                f32x4 c1 = MFMA16(pa[fl][dg], cf, zf, 0, 0, 0);
                nsq[fl] += c1[0] * c1[0] + c1[1] * c1[1]
                         + c1[2] * c1[2] + c1[3] * c1[3];
                half4 h1 = { (_Float16)c1[0], (_Float16)c1[1],
                             (_Float16)c1[2], (_Float16)c1[3] };
                *(half4*)(&WtW[n * 1096 + f_l * 68 + dg * 16 + kc * 4]) = h1;
            }
        }
        // ---- issue pa(it+1) into freed regs ----
        if (it < 7) {
#pragma unroll
            for (int fl = 0; fl < 4; ++fl)
#pragma unroll
                for (int dg = 0; dg < 4; ++dg)
                    pa[fl][dg] = *(const half4*)(qP + fl * 8192 + dg * 256);
        }
        // ---- consume(it-1): 2 d-subs per li ----
        if (it > 0) {
#pragma unroll
            for (int li = 0; li < 4; ++li) {
                int l = w * 4 + li;
                half8 wUa = *(const half8*)(&WtR[l * 1096 + n * 68 + kc * 8]);
                half8 wUb = *(const half8*)(&WtR[l * 1096 + n * 68 + 32 + kc * 8]);
                aU[li] = MFMA_F16(xfa[li], wUa, aU[li], 0, 0, 0);
                aU[li] = MFMA_F16(xfb[li], wUb, aU[li], 0, 0, 0);
            }
        }
        // ---- load xf(it): two 32-d halves (1KB dense each) ----
#pragma unroll
        for (int li = 0; li < 4; ++li) {
            xfa[li] = *(const half8*)(pXA + li * 8192);
            xfb[li] = *(const half8*)(pXA + 512 + li * 8192);
        }
        pXA += 1024;
        qP += 1024;
        LDS_BARRIER();   // drain DS only; global prefetches stay in flight
    }
    // ---- tail consume (chunk 7, buffer 1) ----
#pragma unroll
    for (int li = 0; li < 4; ++li) {
        int l = w * 4 + li;
        half8 wUa = *(const half8*)(&Wt[1][l * 1096 + n * 68 + kc * 8]);
        half8 wUb = *(const half8*)(&Wt[1][l * 1096 + n * 68 + 32 + kc * 8]);
        aU[li] = MFMA_F16(xfa[li], wUa, aU[li], 0, 0, 0);
        aU[li] = MFMA_F16(xfb[li], wUb, aU[li], 0, 0, 0);
    }

    // ---- norm reduce ----
#pragma unroll
    for (int fl = 0; fl < 4; ++fl) {
        float vU = nsq[fl];
        vU += __shfl_xor(vU, 16); vU += __shfl_xor(vU, 32);
        if (kc == 0) CN[n * 16 + w * 4 + fl] = vU;
    }
    __syncthreads();

    int f = f0 + n;
    float sc = mh ? (fabsf(vsp[f]) * 22.627416997969522f)   // vs = |vsp|*sqrt(512)
                  : fabsf(usp[f]);                          // us = |usp|
    _Float16* Out = mh ? S : U2;
#pragma unroll
    for (int li = 0; li < 4; ++li) {
        int lgl = lg * 16 + w * 4 + li;
        float r1 = 1.f / fmaxf(sqrtf(CN[(w * 4 + li) * 16 + n]), 1e-12f);
#pragma unroll
        for (int i = 0; i < 4; ++i) {
            float val = aU[li][i] * r1 * sc;       // us*u'  or  vs*v'
            if (mh) val = val / (1.f + __expf(-val));   // silu(vs*v')
            // layout [l][f>>3][b][8]
            Out[(((size_t)lgl * 128 + (f >> 3)) * 16 + kc * 4 + i) * 8 + (f & 7)] =
                (_Float16)val;
        }
    }
}

// ---------------------------------------------------------------------------
// down_fast (R19): 1024 blocks = 4 zh x 8 lg x 32 d-tiles, 256 thr.
// FK=64: 4 iterations of 64-f chunks. Same stride-1096 Wt.
// ---------------------------------------------------------------------------
__global__ __launch_bounds__(256, 2) void down_fast(
    const _Float16* __restrict__ P3, const float* __restrict__ tc3,
    const _Float16* __restrict__ S, const _Float16* __restrict__ U2,
    float* __restrict__ Rp, float* __restrict__ Np)
{
    int zh = blockIdx.x >> 8;          // 0..3
    int rem = blockIdx.x & 255;
    int lg = rem >> 5;
    int d0 = (rem & 31) * 16;
    int tid = threadIdx.x;
    int w = tid >> 6, lane = tid & 63;
    int n = lane & 15, kc = lane >> 4;

    __shared__ __align__(16) _Float16 Wt[2][16 * 1096]; // [buf][l*1096+d*68+f64]
    __shared__ float CN[256];

    // element-unit base pointers (advance +1024 per 64-f chunk)
    const _Float16* pP3 = P3 + ((size_t)(d0 + w * 4) * 1024 + zh * 256 + n) * 16 + kc * 4;
    size_t hoff = (((size_t)(lg * 16 + w * 4) * 128 + zh * 32 + kc) * 16 + n) * 8;
    const _Float16* pS = S + hoff;
    const _Float16* pU = U2 + hoff;

    half4 pa[4][4];
    // ---- prologue: issue pa(0) (f 0..63 of this zh quarter) ----
#pragma unroll
    for (int dl = 0; dl < 4; ++dl)
#pragma unroll
        for (int fg = 0; fg < 4; ++fg)
            pa[dl][fg] = *(const half4*)(pP3 + dl * 16384 + fg * 256);
    const _Float16* qP3 = pP3 + 1024;

    if (tid < 16) {
        const float* row = tc3 + (size_t)(lg * 16 + tid) * 16;
        float e[16], m = -1e30f, sum = 0.f;
#pragma unroll
        for (int k = 0; k < 16; ++k) m = fmaxf(m, row[k]);
#pragma unroll
        for (int k = 0; k < 16; ++k) { e[k] = __expf(row[k] - m); sum += e[k]; }
        float r = 1.f / sum;
#pragma unroll
        for (int k = 0; k < 16; ++k) CN[tid * 16 + k] = e[k] * r;
    }
    __syncthreads();

    half4 cf3;
#pragma unroll
    for (int j = 0; j < 4; ++j)
        cf3[j] = (_Float16)CN[n * 16 + kc * 4 + j];

    f32x4 zf = { 0.f, 0.f, 0.f, 0.f };
    f32x4 aO[4];
#pragma unroll
    for (int i = 0; i < 4; ++i) aO[i] = zf;
    float nsqD[4] = { 0.f, 0.f, 0.f, 0.f };
    half8 hfa[4], hfb[4];

#pragma unroll 1
    for (int it = 0; it < 4; ++it) {
        _Float16* WtW = &Wt[it & 1][0];
        const _Float16* WtR = &Wt[(it & 1) ^ 1][0];

        // ---- mix(it): 16 K=16 MFMAs over f 0..63 ----
#pragma unroll
        for (int dl = 0; dl < 4; ++dl) {
            int d_l = w * 4 + dl;
#pragma unroll
            for (int fg = 0; fg < 4; ++fg) {
                f32x4 cw = MFMA16(pa[dl][fg], cf3, zf, 0, 0, 0);
                nsqD[dl] += cw[0] * cw[0] + cw[1] * cw[1]
                          + cw[2] * cw[2] + cw[3] * cw[3];
                half4 h4 = { (_Float16)cw[0], (_Float16)cw[1],
                             (_Float16)cw[2], (_Float16)cw[3] };
                *(half4*)(&WtW[n * 1096 + d_l * 68 + fg * 16 + kc * 4]) = h4;
            }
        }
        // ---- issue pa(it+1) ----
        if (it < 3) {
#pragma unroll
            for (int dl = 0; dl < 4; ++dl)
#pragma unroll
                for (int fg = 0; fg < 4; ++fg)
                    pa[dl][fg] = *(const half4*)(qP3 + dl * 16384 + fg * 256);
        }
        // ---- consume(it-1): 2 f-subs per li ----
        if (it > 0) {
#pragma unroll
            for (int li = 0; li < 4; ++li) {
                int l = w * 4 + li;
                half8 wfa = *(const half8*)(&WtR[l * 1096 + n * 68 + kc * 8]);
                half8 wfb = *(const half8*)(&WtR[l * 1096 + n * 68 + 32 + kc * 8]);
                aO[li] = MFMA_F16(hfa[li], wfa, aO[li], 0, 0, 0);
                aO[li] = MFMA_F16(hfb[li], wfb, aO[li], 0, 0, 0);
            }
        }
        // ---- load hf(it) = S*U2, two 32-f halves ----
#pragma unroll
        for (int li = 0; li < 4; ++li) {
            half8 s0 = *(const half8*)(pS + li * 16384);
            half8 u0 = *(const half8*)(pU + li * 16384);
            hfa[li] = s0 * u0;
            half8 s1 = *(const half8*)(pS + 512 + li * 16384);
            half8 u1 = *(const half8*)(pU + 512 + li * 16384);
            hfb[li] = s1 * u1;
        }
        pS += 1024;
        pU += 1024;
        qP3 += 1024;
        LDS_BARRIER();
    }
    // ---- tail consume (chunk 3, buffer 1) ----
#pragma unroll
    for (int li = 0; li < 4; ++li) {
        int l = w * 4 + li;
        half8 wfa = *(const half8*)(&Wt[1][l * 1096 + n * 68 + kc * 8]);
        half8 wfb = *(const half8*)(&Wt[1][l * 1096 + n * 68 + 32 + kc * 8]);
        aO[li] = MFMA_F16(hfa[li], wfa, aO[li], 0, 0, 0);
        aO[li] = MFMA_F16(hfb[li], wfb, aO[li], 0, 0, 0);
    }

#pragma unroll
    for (int dl = 0; dl < 4; ++dl) {
        float v = nsqD[dl];
        v += __shfl_xor(v, 16); v += __shfl_xor(v, 32);
        if (kc == 0)
            Np[(size_t)zh * 65536 + (size_t)(lg * 16 + n) * 512 + d0 + w * 4 + dl] = v;
    }
#pragma unroll
    for (int li = 0; li < 4; ++li) {
        int lgl = lg * 16 + w * 4 + li;
#pragma unroll
        for (int i = 0; i < 4; ++i)
            Rp[(size_t)zh * 1048576 +
               ((size_t)(kc * 4 + i) * 128 + lgl) * 512 + d0 + n] = aO[li][i];
    }
}

// ---------------------------------------------------------------------------
__global__ __launch_bounds__(128) void final_combine(
    const float* __restrict__ Rp, const float* __restrict__ Np,
    float* __restrict__ out)
{
    int rid = blockIdx.x;              // b*128 + l
    int l = rid & 127;
    int t = threadIdx.x;
    f32x4 r = { 0.f, 0.f, 0.f, 0.f };
    f32x4 nn = { 0.f, 0.f, 0.f, 0.f };
#pragma unroll
    for (int zh = 0; zh < 4; ++zh) {
        f32x4 rz = *(const f32x4*)(Rp + (size_t)zh * 1048576 + (size_t)rid * 512 + t * 4);
        f32x4 nz = *(const f32x4*)(Np + (size_t)zh * 65536 + (size_t)l * 512 + t * 4);
#pragma unroll
        for (int j = 0; j < 4; ++j) { r[j] += rz[j]; nn[j] += nz[j]; }
    }
    f32x4 y;
#pragma unroll
    for (int j = 0; j < 4; ++j) {
        float rr = 1.f / fmaxf(sqrtf(fmaxf(nn[j], 0.f)), 1e-12f);
        y[j] = r[j] * rr;
    }
    float s = y[0] * y[0] + y[1] * y[1] + y[2] * y[2] + y[3] * y[3];
#pragma unroll
    for (int off = 32; off > 0; off >>= 1) s += __shfl_down(s, off);
    __shared__ float sred[2];
    if ((t & 63) == 0) sred[t >> 6] = s;
    __syncthreads();
    float rr = 1.f / fmaxf(sqrtf(sred[0] + sred[1]), 1e-12f);
    f32x4 o = { y[0] * rr, y[1] * rr, y[2] * rr, y[3] * rr };
    *(f32x4*)(out + (size_t)rid * 512 + t * 4) = o;
}

// ===========================================================================
// SLOW FALLBACK (round-2 kernels, proven) — used when ws_size < WS_FAST
// ===========================================================================
__global__ __launch_bounds__(256) void up_kernel(
    const float* __restrict__ x,
    const float* __restrict__ wg, const float* __restrict__ wu,
    const float* __restrict__ tc1, const float* __restrict__ tc2,
    const float* __restrict__ usp, const float* __restrict__ vsp,
    _Float16* __restrict__ Hp)
{
    int lg = blockIdx.x >> 6;
    int f0 = (blockIdx.x & 63) * 16;
    int tid = threadIdx.x;
    int w = tid >> 6, lane = tid & 63;
    int n = lane & 15, kc = lane >> 4;

    __shared__ __align__(16) _Float16 Xt[256 * 40];
    __shared__ __align__(16) _Float16 Bh[32 * 16 * 24];
    __shared__ __align__(16) _Float16 Wt[16 * 528];
    __shared__ float CN[2 * 16 * 16];

    if (tid < 32) {
        int s = tid >> 4, ll = tid & 15;
        const float* row = (s ? tc2 : tc1) + (size_t)(lg * 16 + ll) * 16;
        float e[16], m = -1e30f, sum = 0.f;
#pragma unroll
        for (int k = 0; k < 16; ++k) m = fmaxf(m, row[k]);
#pragma unroll
        for (int k = 0; k < 16; ++k) { e[k] = __expf(row[k] - m); sum += e[k]; }
        float r = 1.f / sum;
#pragma unroll
        for (int k = 0; k < 16; ++k) CN[s * 256 + ll * 16 + k] = e[k] * r;
    }
    __syncthreads();

    half8 cf1 = { 0, 0, 0, 0, 0, 0, 0, 0 };
    half8 cf2 = { 0, 0, 0, 0, 0, 0, 0, 0 };
    if (kc < 2) {
#pragma unroll
        for (int j = 0; j < 8; ++j) {
            cf1[j] = (_Float16)CN[0 * 256 + n * 16 + kc * 8 + j];
            cf2[j] = (_Float16)CN[1 * 256 + n * 16 + kc * 8 + j];
        }
    }

    f32x4 zf = { 0.f, 0.f, 0.f, 0.f };
    f32x4 aU[4], aV[4];
#pragma unroll
    for (int i = 0; i < 4; ++i) { aU[i] = zf; aV[i] = zf; }
    float nsqU[4] = { 0.f, 0.f, 0.f, 0.f };
    float nsqV[4] = { 0.f, 0.f, 0.f, 0.f };

    for (int it = 0; it < 16; ++it) {
        int d0 = it * 32;
#pragma unroll
        for (int p = 0; p < 8; ++p) {
            int r = p * 32 + (tid >> 3);
            int fj = tid & 7;
            int ll = r >> 4, b = r & 15;
            f32x4 v = *(const f32x4*)(
                x + ((size_t)(b * 128 + lg * 16 + ll) * 512 + d0 + fj * 4));
            half4 h = { (_Float16)v[0], (_Float16)v[1],
                        (_Float16)v[2], (_Float16)v[3] };
            *(half4*)(&Xt[r * 40 + fj * 4]) = h;
        }
#pragma unroll
        for (int p = 0; p < 8; ++p) {
            int idx = p * 256 + tid;
            int q = idx & 3, dd = (idx >> 2) & 31, k = idx >> 7;
            f32x4 v = *(const f32x4*)(
                wg + ((size_t)k * 512 + d0 + dd) * 1024 + f0 + q * 4);
#pragma unroll
            for (int j = 0; j < 4; ++j)
                Bh[(dd * 16 + q * 4 + j) * 24 + k] = (_Float16)v[j];
        }
        __syncthreads();
#pragma unroll
        for (int fl = 0; fl < 4; ++fl) {
            int f_l = w * 4 + fl;
#pragma unroll
            for (int dg = 0; dg < 2; ++dg) {
                half8 a = { 0, 0, 0, 0, 0, 0, 0, 0 };
                if (kc < 2)
                    a = *(const half8*)(&Bh[((dg * 16 + n) * 16 + f_l) * 24 + kc * 8]);
                f32x4 cw = MFMA_F16(a, cf1, zf, 0, 0, 0);
                nsqU[fl] += cw[0] * cw[0] + cw[1] * cw[1]
                          + cw[2] * cw[2] + cw[3] * cw[3];
                half4 h4 = { (_Float16)cw[0], (_Float16)cw[1],
                             (_Float16)cw[2], (_Float16)cw[3] };
                *(half4*)(&Wt[n * 528 + f_l * 32 + dg * 16 + kc * 4]) = h4;
            }
        }
        __syncthreads();
#pragma unroll
        for (int li = 0; li < 4; ++li) {
            int l = w * 4 + li;
            half8 xf = *(const half8*)(&Xt[(l * 16 + n) * 40 + kc * 8]);
            half8 wf = *(const half8*)(&Wt[l * 528 + n * 32 + kc * 8]);
            aU[li] = MFMA_F16(xf, wf, aU[li], 0, 0, 0);
        }
#pragma unroll
        for (int p = 0; p < 8; ++p) {
            int idx = p * 256 + tid;
            int q = idx & 3, dd = (idx >> 2) & 31, k = idx >> 7;
            f32x4 v = *(const f32x4*)(
                wu + ((size_t)k * 512 + d0 + dd) * 1024 + f0 + q * 4);
#pragma unroll
            for (int j = 0; j < 4; ++j)
                Bh[(dd * 16 + q * 4 + j) * 24 + k] = (_Float16)v[j];
        }
        __syncthreads();
#pragma unroll
        for (int fl = 0; fl < 4; ++fl) {
            int f_l = w * 4 + fl;
#pragma unroll
            for (int dg = 0; dg < 2; ++dg) {
                half8 a = { 0, 0, 0, 0, 0, 0, 0, 0 };
                if (kc < 2)
                    a = *(const half8*)(&Bh[((dg * 16 + n) * 16 + f_l) * 24 + kc * 8]);
                f32x4 cw = MFMA_F16(a, cf2, zf, 0, 0, 0);
                nsqV[fl] += cw[0] * cw[0] + cw[1] * cw[1]
                          + cw[2] * cw[2] + cw[3] * cw[3];
                half4 h4 = { (_Float16)cw[0], (_Float16)cw[1],
                             (_Float16)cw[2], (_Float16)cw[3] };
                *(half4*)(&Wt[n * 528 + f_l * 32 + dg * 16 + kc * 4]) = h4;
            }
        }
        __syncthreads();
#pragma unroll
        for (int li = 0; li < 4; ++li) {
            int l = w * 4 + li;
            half8 xf = *(const half8*)(&Xt[(l * 16 + n) * 40 + kc * 8]);
            half8 wf = *(const half8*)(&Wt[l * 528 + n * 32 + kc * 8]);
            aV[li] = MFMA_F16(xf, wf, aV[li], 0, 0, 0);
        }
        __syncthreads();
    }

#pragma unroll
    for (int fl = 0; fl < 4; ++fl) {
        float vU = nsqU[fl], vV = nsqV[fl];
        vU += __shfl_xor(vU, 16); vU += __shfl_xor(vU, 32);
        vV += __shfl_xor(vV, 16); vV += __shfl_xor(vV, 32);
        if (kc == 0) {
            CN[0 * 256 + n * 16 + w * 4 + fl] = vU;
            CN[1 * 256 + n * 16 + w * 4 + fl] = vV;
        }
    }
    __syncthreads();

    int f = f0 + n;
    float usv = fabsf(usp[f]);
    float vsv = fabsf(vsp[f]) * 22.627416997969522f;
#pragma unroll
    for (int li = 0; li < 4; ++li) {
        int lgl = lg * 16 + w * 4 + li;
        float r1 = 1.f / fmaxf(sqrtf(CN[0 * 256 + (w * 4 + li) * 16 + n]), 1e-12f);
        float r2 = 1.f / fmaxf(sqrtf(CN[1 * 256 + (w * 4 + li) * 16 + n]), 1e-12f);
#pragma unroll
        for (int i = 0; i < 4; ++i) {
            float u = aU[li][i] * r1;
            float v = aV[li][i] * r2;
            float zz = vsv * v;
            float sil = zz / (1.f + __expf(-zz));
            float h = sil * (usv * u);
            Hp[((size_t)lgl * 16 + kc * 4 + i) * 1024 + f] = (_Float16)h;
        }
    }
}

__global__ __launch_bounds__(256) void down_kernel(
    const float* __restrict__ wd, const float* __restrict__ tc3,
    const _Float16* __restrict__ Hp, float* __restrict__ out)
{
    int lg = blockIdx.x >> 5;
    int d0 = (blockIdx.x & 31) * 16;
    int tid = threadIdx.x;
    int w = tid >> 6, lane = tid & 63;
    int n = lane & 15, kc = lane >> 4;

    __shared__ __align__(16) _Float16 Ht[256 * 40];
    __shared__ __align__(16) _Float16 Bh[32 * 16 * 24];
    __shared__ __align__(16) _Float16 Wt[16 * 528];
    __shared__ float CN[16 * 16];

    if (tid < 16) {
        const float* row = tc3 + (size_t)(lg * 16 + tid) * 16;
        float e[16], m = -1e30f, sum = 0.f;
#pragma unroll
        for (int k = 0; k < 16; ++k) m = fmaxf(m, row[k]);
#pragma unroll
        for (int k = 0; k < 16; ++k) { e[k] = __expf(row[k] - m); sum += e[k]; }
        float r = 1.f / sum;
#pragma unroll
        for (int k = 0; k < 16; ++k) CN[tid * 16 + k] = e[k] * r;
    }
    __syncthreads();

    half8 cf3 = { 0, 0, 0, 0, 0, 0, 0, 0 };
    if (kc < 2) {
#pragma unroll
        for (int j = 0; j < 8; ++j)
            cf3[j] = (_Float16)CN[n * 16 + kc * 8 + j];
    }

    f32x4 zf = { 0.f, 0.f, 0.f, 0.f };
    f32x4 aO[4];
#pragma unroll
    for (int i = 0; i < 4; ++i) aO[i] = zf;
    float nsqD[4] = { 0.f, 0.f, 0.f, 0.f };

    for (int it = 0; it < 32; ++it) {
        int f0 = it * 32;
#pragma unroll
        for (int p = 0; p < 8; ++p) {
            int r = p * 32 + (tid >> 3);
            int hj = tid & 7;
            int ll = r >> 4, b = r & 15;
            half4 v = *(const half4*)(
                Hp + ((size_t)(lg * 16 + ll) * 16 + b) * 1024 + f0 + hj * 4);
            *(half4*)(&Ht[r * 40 + hj * 4]) = v;
        }
#pragma unroll
        for (int p = 0; p < 8; ++p) {
            int idx = p * 256 + tid;
            int q = idx & 3, ff = (idx >> 2) & 31, k = idx >> 7;
            f32x4 v = *(const f32x4*)(
                wd + ((size_t)k * 1024 + f0 + ff) * 512 + d0 + q * 4);
#pragma unroll
            for (int j = 0; j < 4; ++j)
                Bh[(ff * 16 + q * 4 + j) * 24 + k] = (_Float16)v[j];
        }
        __syncthreads();
#pragma unroll
        for (int dl = 0; dl < 4; ++dl) {
            int d_l = w * 4 + dl;
#pragma unroll
            for (int fg = 0; fg < 2; ++fg) {
                half8 a = { 0, 0, 0, 0, 0, 0, 0, 0 };
                if (kc < 2)
                    a = *(const half8*)(&Bh[((fg * 16 + n) * 16 + d_l) * 24 + kc * 8]);
                f32x4 cw = MFMA_F16(a, cf3, zf, 0, 0, 0);
                nsqD[dl] += cw[0] * cw[0] + cw[1] * cw[1]
                          + cw[2] * cw[2] + cw[3] * cw[3];
                half4 h4 = { (_Float16)cw[0], (_Float16)cw[1],
                             (_Float16)cw[2], (_Float16)cw[3] };
                *(half4*)(&Wt[n * 528 + d_l * 32 + fg * 16 + kc * 4]) = h4;
            }
        }
        __syncthreads();
#pragma unroll
        for (int li = 0; li < 4; ++li) {
            int l = w * 4 + li;
            half8 hf = *(const half8*)(&Ht[(l * 16 + n) * 40 + kc * 8]);
            half8 wf = *(const half8*)(&Wt[l * 528 + n * 32 + kc * 8]);
            aO[li] = MFMA_F16(hf, wf, aO[li], 0, 0, 0);
        }
        __syncthreads();
    }

#pragma unroll
    for (int dl = 0; dl < 4; ++dl) {
        float v = nsqD[dl];
        v += __shfl_xor(v, 16); v += __shfl_xor(v, 32);
        if (kc == 0) CN[n * 16 + w * 4 + dl] = v;
    }
    __syncthreads();

#pragma unroll
    for (int li = 0; li < 4; ++li) {
        int lgl = lg * 16 + w * 4 + li;
        float r3 = 1.f / fmaxf(sqrtf(CN[(w * 4 + li) * 16 + n]), 1e-12f);
#pragma unroll
        for (int i = 0; i < 4; ++i)
            out[((size_t)(kc * 4 + i) * 128 + lgl) * 512 + d0 + n] = aO[li][i] * r3;
    }
}

__global__ __launch_bounds__(128) void final_kernel(float* __restrict__ out)
{
    int rid = blockIdx.x;
    int t = threadIdx.x;
    f32x4 y = *(const f32x4*)(out + (size_t)rid * 512 + t * 4);
    float s = y[0] * y[0] + y[1] * y[1] + y[2] * y[2] + y[3] * y[3];
#pragma unroll
    for (int off = 32; off > 0; off >>= 1) s += __shfl_down(s, off);
    __shared__ float sred[2];
    if ((t & 63) == 0) sred[t >> 6] = s;
    __syncthreads();
    float rr = 1.f / fmaxf(sqrtf(sred[0] + sred[1]), 1e-12f);
    f32x4 o = { y[0] * rr, y[1] * rr, y[2] * rr, y[3] * rr };
    *(f32x4*)(out + (size_t)rid * 512 + t * 4) = o;
}

// ---------------------------------------------------------------------------
extern "C" void kernel_launch(void* const* d_in, const int* in_sizes, int n_in,
                              void* d_out, int out_size, void* d_ws, size_t ws_size,
                              hipStream_t stream)
{
    (void)in_sizes; (void)n_in; (void)out_size;
    const float* x   = (const float*)d_in[0];
    const float* wg  = (const float*)d_in[1];
    const float* wu  = (const float*)d_in[2];
    const float* wd  = (const float*)d_in[3];
    const float* tc1 = (const float*)d_in[4];
    const float* tc2 = (const float*)d_in[5];
    const float* tc3 = (const float*)d_in[6];
    const float* usp = (const float*)d_in[7];
    const float* vsp = (const float*)d_in[8];
    float* outp = (float*)d_out;
    char* ws = (char*)d_ws;

    if (ws_size >= WS_FAST) {
        _Float16* P1  = (_Float16*)(ws + OFF_P1);
        _Float16* P2  = (_Float16*)(ws + OFF_P2);
        _Float16* P3n = (_Float16*)(ws + OFF_P3n);  // 17..33 MiB (after Np)
        _Float16* XA  = (_Float16*)(ws + OFF_XA);   // 32..34 MiB
        _Float16* U2  = (_Float16*)(ws + OFF_U2);   // 34..38 MiB
        _Float16* S   = (_Float16*)(ws + OFF_S);    // 38..42 MiB
        float* Rp = (float*)(ws + OFF_P1);   // overlays P1 (dead after up)
        float* Np = (float*)(ws + OFF_P2);   // 16..17 MiB (P2 dead after up)
        prep_basis_all<<<dim3(512, 2), dim3(256), 0, stream>>>(
            wg, wu, wd, P1, P2, P3n, 0);                   // P1, P2
        prep_x<<<dim3(256), dim3(256), 0, stream>>>(x, XA);
        up_split<<<dim3(1024), dim3(256), 0, stream>>>(P1, P2, XA, tc1, tc2,
                                                       usp, vsp, U2, S);
        prep_basis_all<<<dim3(512, 1), dim3(256), 0, stream>>>(
            wg, wu, wd, P1, P2, P3n, 2);                   // P3 at 17 MiB
        down_fast<<<dim3(1024), dim3(256), 0, stream>>>(P3n, tc3, S, U2, Rp, Np);
        final_combine<<<dim3(2048), dim3(128), 0, stream>>>(Rp, Np, outp);
    } else {
        _Float16* Hp = (_Float16*)ws;
        up_kernel<<<dim3(512), dim3(256), 0, stream>>>(x, wg, wu, tc1, tc2,
                                                       usp, vsp, Hp);
        down_kernel<<<dim3(256), dim3(256), 0, stream>>>(wd, tc3, Hp, outp);
        final_kernel<<<dim3(2048), dim3(128), 0, stream>>>(outp);
    }
}

// Round 13
// 225.143 us; speedup vs baseline: 1.0503x; 1.0503x over previous
//
#include <hip/hip_runtime.h>
#include <hip/hip_bf16.h>
#include <cmath>

// ---------------------------------------------------------------------------
// NPerTokenSwishGLU_Basis — fused f16-MFMA implementation (gfx950), round 20.
//
// R19 post-mortem: fewer iterations REGRESSED (54.2us, FETCH +7MB) — 13th
// null/regression on up/down internals; that structure's floor (~50+~47us)
// is established by exhaustion. Ledger: kernel sum ~130-140us vs 228 total
// -> ~90us of inter-launch overhead across 6 serialized dispatches is the
// largest unattacked item. R20: merge the three independent pre-up kernels
// (prep z0, prep z1, prep_x) into ONE prep_pre launch (grid 1280, branch on
// blockIdx, block-uniform -> barriers safe, LDS unioned). 6 -> 5 launches.
// up/down/final are byte-identical R17 (proven 225-229 band) as controls.
// ---------------------------------------------------------------------------

typedef _Float16 half8 __attribute__((ext_vector_type(8)));
typedef _Float16 half4 __attribute__((ext_vector_type(4)));
typedef float    f32x4 __attribute__((ext_vector_type(4)));
typedef float    f32x2 __attribute__((ext_vector_type(2)));

#define MFMA_F16  __builtin_amdgcn_mfma_f32_16x16x32_f16
#define MFMA16    __builtin_amdgcn_mfma_f32_16x16x16f16

// LDS-only barrier: drain DS ops, leave global loads in flight.
#define LDS_BARRIER()                                           \
    do {                                                        \
        asm volatile("s_waitcnt lgkmcnt(0)" ::: "memory");      \
        __builtin_amdgcn_s_barrier();                           \
    } while (0)

static constexpr size_t OFF_P1  = 0;            // 16 MiB; Rp overlay (down)
static constexpr size_t OFF_P2  = 16777216;     // 16 MiB; Np overlay (down, 1 MiB)
static constexpr size_t OFF_P3n = 17825792;     // 16 MiB at 17 MiB (after Np)
static constexpr size_t OFF_XA  = 33554432;     // 2 MiB at 32 MiB
static constexpr size_t OFF_U2  = 35651584;     // 4 MiB at 34 MiB
static constexpr size_t OFF_S   = 39845888;     // 4 MiB at 38 MiB (top 42 MiB)
static constexpr size_t WS_FAST = 54525952;     // 52 MiB (proven)

// ---------------------------------------------------------------------------
// prep_pre (R20): ONE launch for all pre-up prep.
//   blocks 0..1023  : prep_basis z = bid>>9 (wg->P1, wu->P2), 32x32 tiles
//   blocks 1024..1279: prep_x (x fp32 [b][l][d] -> XA f16 [l][d>>3][b][8])
// Branch is block-uniform; LDS unioned (prep_basis 69632 B dominates).
// ---------------------------------------------------------------------------
__global__ __launch_bounds__(256) void prep_pre(
    const float* __restrict__ x,
    const float* __restrict__ wg, const float* __restrict__ wu,
    _Float16* __restrict__ P1, _Float16* __restrict__ P2,
    _Float16* __restrict__ XA)
{
    __shared__ __align__(16) float Smem[16 * 1088];   // 69632 B union
    int t = threadIdx.x;
    int bid = blockIdx.x;

    if (bid < 1024) {
        // ---- prep_basis z0/z1: (K,512,1024)=[k][d][f] -> P[f][d][k] ----
        int z  = bid >> 9;
        int bx = bid & 511;
        const float* src = z ? wu : wg;
        _Float16*    dst = z ? P2 : P1;
        const int Amin = 512, Bmaj = 1024, nM = 32;
        int m0 = (bx / nM) * 32;
        int M0 = (bx % nM) * 32;
        float* S = Smem;

        int row = t >> 3;                    // 0..31 (minor row)
        int cg  = t & 7;                     // 0..7 (16B col group)
#pragma unroll
        for (int k = 0; k < 16; ++k) {
            f32x4 v = *(const f32x4*)(
                src + (size_t)k * Amin * Bmaj + (size_t)(m0 + row) * Bmaj + M0 + cg * 4);
            f32x2 lo = { v[0], v[1] };
            f32x2 hi = { v[2], v[3] };
            *(f32x2*)(&S[k * 1088 + row * 34 + cg * 4])     = lo;
            *(f32x2*)(&S[k * 1088 + row * 34 + cg * 4 + 2]) = hi;
        }
        __syncthreads();

        int mn = t & 31, mjq = t >> 5;
#pragma unroll
        for (int q = 0; q < 4; ++q) {
            int mj = q * 8 + mjq;
            half8 v0, v1;
#pragma unroll
            for (int k = 0; k < 8; ++k) v0[k] = (_Float16)S[k * 1088 + mn * 34 + mj];
#pragma unroll
            for (int k = 0; k < 8; ++k) v1[k] = (_Float16)S[(k + 8) * 1088 + mn * 34 + mj];
            _Float16* out = dst + ((size_t)(M0 + mj) * Amin + m0 + mn) * 16;
            *(half8*)out       = v0;
            *(half8*)(out + 8) = v1;
        }
    } else {
        // ---- prep_x ----
        int bx = bid - 1024;
        int l = bx >> 1, bh = bx & 1;
        _Float16* XT = (_Float16*)Smem;      // [8][524]

        int bl = t >> 5, q = t & 31;          // b-local 0..7, q 0..31
        int b = bh * 8 + bl;
#pragma unroll
        for (int j = 0; j < 4; ++j) {
            f32x4 v = *(const f32x4*)(x + ((size_t)(b * 128 + l) * 512 + j * 128 + q * 4));
#pragma unroll
            for (int i = 0; i < 4; ++i)
                XT[bl * 524 + j * 128 + q * 4 + i] = (_Float16)v[i];
        }
        __syncthreads();

        int c = t >> 2, bi = t & 3;           // c 0..63
#pragma unroll
        for (int s = 0; s < 2; ++s) {
            int blw = bi * 2 + s;             // 0..7
            half8 h = *(const half8*)(&XT[blw * 524 + c * 8]);
            *(half8*)(XA + (((size_t)(l * 64 + c) * 16 + bh * 8 + blw) * 8)) = h;
        }
    }
}

// ---------------------------------------------------------------------------
// prep_basis_all (z=2 only now): wd (K,1024,512)=[k][f][d] -> P3[d][f][k]
// ---------------------------------------------------------------------------
__global__ __launch_bounds__(256) void prep_basis_all(
    const float* __restrict__ wg, const float* __restrict__ wu,
    const float* __restrict__ wd,
    _Float16* __restrict__ P1, _Float16* __restrict__ P2,
    _Float16* __restrict__ P3, int zoff)
{
    int z = blockIdx.y + zoff;
    const float* src = (z == 0) ? wg : (z == 1) ? wu : wd;
    _Float16*    dst = (z == 0) ? P1 : (z == 1) ? P2 : P3;
    int Amin = (z == 2) ? 1024 : 512;    // minor-dim size
    int Bmaj = (z == 2) ? 512 : 1024;    // major-dim size
    int nM = Bmaj >> 5;
    int m0 = (blockIdx.x / nM) * 32;     // minor base
    int M0 = (blockIdx.x % nM) * 32;     // major base

    __shared__ float S[16 * 1088];       // [k][row*34 + col]
    int t = threadIdx.x;

    int row = t >> 3;                    // 0..31 (minor row)
    int cg  = t & 7;                     // 0..7 (16B col group)
#pragma unroll
    for (int k = 0; k < 16; ++k) {
        f32x4 v = *(const f32x4*)(
            src + (size_t)k * Amin * Bmaj + (size_t)(m0 + row) * Bmaj + M0 + cg * 4);
        f32x2 lo = { v[0], v[1] };
        f32x2 hi = { v[2], v[3] };
        *(f32x2*)(&S[k * 1088 + row * 34 + cg * 4])     = lo;
        *(f32x2*)(&S[k * 1088 + row * 34 + cg * 4 + 2]) = hi;
    }
    __syncthreads();

    int mn = t & 31, mjq = t >> 5;
#pragma unroll
    for (int q = 0; q < 4; ++q) {
        int mj = q * 8 + mjq;
        half8 v0, v1;
#pragma unroll
        for (int k = 0; k < 8; ++k) v0[k] = (_Float16)S[k * 1088 + mn * 34 + mj];
#pragma unroll
        for (int k = 0; k < 8; ++k) v1[k] = (_Float16)S[(k + 8) * 1088 + mn * 34 + mj];
        _Float16* out = dst + ((size_t)(M0 + mj) * Amin + m0 + mn) * 16;
        *(half8*)out       = v0;
        *(half8*)(out + 8) = v1;
    }
}

// ---------------------------------------------------------------------------
// up_split (R17, proven): 1024 blocks = mh(2) x 8 lg x 64 f-tiles, 256 thr.
// ---------------------------------------------------------------------------
__global__ __launch_bounds__(256, 4) void up_split(
    const _Float16* __restrict__ P1, const _Float16* __restrict__ P2,
    const _Float16* __restrict__ XA,
    const float* __restrict__ tc1, const float* __restrict__ tc2,
    const float* __restrict__ usp, const float* __restrict__ vsp,
    _Float16* __restrict__ U2, _Float16* __restrict__ S)
{
    int bid = blockIdx.x;
    int mh = bid >> 9;                  // 0: gate/u, 1: up/v
    int lg = (bid >> 6) & 7;
    int f0 = (bid & 63) * 16;
    int tid = threadIdx.x;
    int w = tid >> 6, lane = tid & 63;
    int n = lane & 15, kc = lane >> 4;

    const _Float16* P  = mh ? P2 : P1;
    const float*    tc = mh ? tc2 : tc1;

    __shared__ __align__(16) _Float16 Wt[2][16 * 584]; // [buf][l*584+f*36+d]
    __shared__ float CN[256];

    // element-unit base pointers (advance +512 per 32-d chunk)
    const _Float16* pP  = P + ((size_t)(f0 + w * 4) * 512 + n) * 16 + kc * 4;
    const _Float16* pXA = XA + (((size_t)(lg * 16 + w * 4) * 64 + kc) * 16 + n) * 8;

    half4 pa[4][2];
    // ---- prologue: issue pa(0); softmax + barrier cover the latency ----
#pragma unroll
    for (int fl = 0; fl < 4; ++fl)
#pragma unroll
        for (int dg = 0; dg < 2; ++dg)
            pa[fl][dg] = *(const half4*)(pP + fl * 8192 + dg * 256);
    const _Float16* qP = pP + 512;

    if (tid < 16) {
        const float* row = tc + (size_t)(lg * 16 + tid) * 16;
        float e[16], m = -1e30f, sum = 0.f;
#pragma unroll
        for (int k = 0; k < 16; ++k) m = fmaxf(m, row[k]);
#pragma unroll
        for (int k = 0; k < 16; ++k) { e[k] = __expf(row[k] - m); sum += e[k]; }
        float r = 1.f / sum;
#pragma unroll
        for (int k = 0; k < 16; ++k) CN[tid * 16 + k] = e[k] * r;
    }
    __syncthreads();

    half4 cf;
#pragma unroll
    for (int j = 0; j < 4; ++j)
        cf[j] = (_Float16)CN[n * 16 + kc * 4 + j];

    f32x4 zf = { 0.f, 0.f, 0.f, 0.f };
    f32x4 aU[4];
#pragma unroll
    for (int i = 0; i < 4; ++i) aU[i] = zf;
    float nsq[4] = { 0.f, 0.f, 0.f, 0.f };
    half8 xf[4];

#pragma unroll 1
    for (int it = 0; it < 16; ++it) {
        _Float16* WtW = &Wt[it & 1][0];
        const _Float16* WtR = &Wt[(it & 1) ^ 1][0];

        // ---- mix(it) (pa in flight; compiler waits vmcnt), K=16 MFMA ----
#pragma unroll
        for (int fl = 0; fl < 4; ++fl) {
            int f_l = w * 4 + fl;
#pragma unroll
            for (int dg = 0; dg < 2; ++dg) {
                f32x4 c1 = MFMA16(pa[fl][dg], cf, zf, 0, 0, 0);
                nsq[fl] += c1[0] * c1[0] + c1[1] * c1[1]
                         + c1[2] * c1[2] + c1[3] * c1[3];
                half4 h1 = { (_Float16)c1[0], (_Float16)c1[1],
                             (_Float16)c1[2], (_Float16)c1[3] };
                *(half4*)(&WtW[n * 584 + f_l * 36 + dg * 16 + kc * 4]) = h1;
            }
        }
        // ---- issue pa(it+1) into freed regs ----
        if (it < 15) {
#pragma unroll
            for (int fl = 0; fl < 4; ++fl)
#pragma unroll
                for (int dg = 0; dg < 2; ++dg)
                    pa[fl][dg] = *(const half4*)(qP + fl * 8192 + dg * 256);
        }
        // ---- consume(it-1) from the other buffer ----
        if (it > 0) {
#pragma unroll
            for (int li = 0; li < 4; ++li) {
                int l = w * 4 + li;
                half8 wU = *(const half8*)(&WtR[l * 584 + n * 36 + kc * 8]);
                aU[li] = MFMA_F16(xf[li], wU, aU[li], 0, 0, 0);
            }
        }
        // ---- load xf(it): 1KB dense per wave ----
#pragma unroll
        for (int li = 0; li < 4; ++li)
            xf[li] = *(const half8*)(pXA + li * 8192);
        pXA += 512;
        qP += 512;
        LDS_BARRIER();   // drain DS only; global prefetches stay in flight
    }
    // ---- tail consume (chunk 15, buffer 1) ----
#pragma unroll
    for (int li = 0; li < 4; ++li) {
        int l = w * 4 + li;
        half8 wU = *(const half8*)(&Wt[1][l * 584 + n * 36 + kc * 8]);
        aU[li] = MFMA_F16(xf[li], wU, aU[li], 0, 0, 0);
    }

    // ---- norm reduce ----
#pragma unroll
    for (int fl = 0; fl < 4; ++fl) {
        float vU = nsq[fl];
        vU += __shfl_xor(vU, 16); vU += __shfl_xor(vU, 32);
        if (kc == 0) CN[n * 16 + w * 4 + fl] = vU;
    }
    __syncthreads();

    int f = f0 + n;
    float sc = mh ? (fabsf(vsp[f]) * 22.627416997969522f)   // vs = |vsp|*sqrt(512)
                  : fabsf(usp[f]);                          // us = |usp|
    _Float16* Out = mh ? S : U2;
#pragma unroll
    for (int li = 0; li < 4; ++li) {
        int lgl = lg * 16 + w * 4 + li;
        float r1 = 1.f / fmaxf(sqrtf(CN[(w * 4 + li) * 16 + n]), 1e-12f);
#pragma unroll
        for (int i = 0; i < 4; ++i) {
            float val = aU[li][i] * r1 * sc;       // us*u'  or  vs*v'
            if (mh) val = val / (1.f + __expf(-val));   // silu(vs*v')
            // layout [l][f>>3][b][8]
            Out[(((size_t)lgl * 128 + (f >> 3)) * 16 + kc * 4 + i) * 8 + (f & 7)] =
                (_Float16)val;
        }
    }
}

// ---------------------------------------------------------------------------
// down_fast (R17, proven): 1024 blocks = 4 f-quarters x 8 lg x 32 d-tiles.
// ---------------------------------------------------------------------------
__global__ __launch_bounds__(256, 4) void down_fast(
    const _Float16* __restrict__ P3, const float* __restrict__ tc3,
    const _Float16* __restrict__ S, const _Float16* __restrict__ U2,
    float* __restrict__ Rp, float* __restrict__ Np)
{
    int zh = blockIdx.x >> 8;          // 0..3
    int rem = blockIdx.x & 255;
    int lg = rem >> 5;
    int d0 = (rem & 31) * 16;
    int tid = threadIdx.x;
    int w = tid >> 6, lane = tid & 63;
    int n = lane & 15, kc = lane >> 4;

    __shared__ __align__(16) _Float16 Wt[2][16 * 584];    // [buf][l*584 + d*36 + f]
    __shared__ float CN[256];

    // element-unit base pointers (advance +512 per 32-f chunk)
    const _Float16* pP3 = P3 + ((size_t)(d0 + w * 4) * 1024 + zh * 256 + n) * 16 + kc * 4;
    size_t hoff = (((size_t)(lg * 16 + w * 4) * 128 + zh * 32 + kc) * 16 + n) * 8;
    const _Float16* pS = S + hoff;
    const _Float16* pU = U2 + hoff;

    half4 pa[4][2];
    // ---- prologue: issue pa(0) ----
#pragma unroll
    for (int dl = 0; dl < 4; ++dl)
#pragma unroll
        for (int fg = 0; fg < 2; ++fg)
            pa[dl][fg] = *(const half4*)(pP3 + dl * 16384 + fg * 256);
    const _Float16* qP3 = pP3 + 512;

    if (tid < 16) {
        const float* row = tc3 + (size_t)(lg * 16 + tid) * 16;
        float e[16], m = -1e30f, sum = 0.f;
#pragma unroll
        for (int k = 0; k < 16; ++k) m = fmaxf(m, row[k]);
#pragma unroll
        for (int k = 0; k < 16; ++k) { e[k] = __expf(row[k] - m); sum += e[k]; }
        float r = 1.f / sum;
#pragma unroll
        for (int k = 0; k < 16; ++k) CN[tid * 16 + k] = e[k] * r;
    }
    __syncthreads();

    half4 cf3;
#pragma unroll
    for (int j = 0; j < 4; ++j)
        cf3[j] = (_Float16)CN[n * 16 + kc * 4 + j];

    f32x4 zf = { 0.f, 0.f, 0.f, 0.f };
    f32x4 aO[4];
#pragma unroll
    for (int i = 0; i < 4; ++i) aO[i] = zf;
    float nsqD[4] = { 0.f, 0.f, 0.f, 0.f };
    half8 hf[4];

#pragma unroll 1
    for (int it = 0; it < 8; ++it) {
        _Float16* WtW = &Wt[it & 1][0];
        const _Float16* WtR = &Wt[(it & 1) ^ 1][0];

        // ---- mix(it), K=16 MFMA ----
#pragma unroll
        for (int dl = 0; dl < 4; ++dl) {
            int d_l = w * 4 + dl;
#pragma unroll
            for (int fg = 0; fg < 2; ++fg) {
                f32x4 cw = MFMA16(pa[dl][fg], cf3, zf, 0, 0, 0);
                nsqD[dl] += cw[0] * cw[0] + cw[1] * cw[1]
                          + cw[2] * cw[2] + cw[3] * cw[3];
                half4 h4 = { (_Float16)cw[0], (_Float16)cw[1],
                             (_Float16)cw[2], (_Float16)cw[3] };
                *(half4*)(&WtW[n * 584 + d_l * 36 + fg * 16 + kc * 4]) = h4;
            }
        }
        // ---- issue pa(it+1) ----
        if (it < 7) {
#pragma unroll
            for (int dl = 0; dl < 4; ++dl)
#pragma unroll
                for (int fg = 0; fg < 2; ++fg)
                    pa[dl][fg] = *(const half4*)(qP3 + dl * 16384 + fg * 256);
        }
        // ---- consume(it-1) ----
        if (it > 0) {
#pragma unroll
            for (int li = 0; li < 4; ++li) {
                int l = w * 4 + li;
                half8 wf = *(const half8*)(&WtR[l * 584 + n * 36 + kc * 8]);
                aO[li] = MFMA_F16(hf[li], wf, aO[li], 0, 0, 0);
            }
        }
        // ---- load hf(it) = S * U2 (each 1KB dense per wave) ----
#pragma unroll
        for (int li = 0; li < 4; ++li) {
            half8 s8 = *(const half8*)(pS + li * 16384);
            half8 u8 = *(const half8*)(pU + li * 16384);
            hf[li] = s8 * u8;
        }
        pS += 512;
        pU += 512;
        qP3 += 512;
        LDS_BARRIER();   // drain DS only; global prefetches stay in flight
    }
    // ---- tail consume (chunk 7, buffer 1) ----
#pragma unroll
    for (int li = 0; li < 4; ++li) {
        int l = w * 4 + li;
        half8 wf = *(const half8*)(&Wt[1][l * 584 + n * 36 + kc * 8]);
        aO[li] = MFMA_F16(hf[li], wf, aO[li], 0, 0, 0);
    }

#pragma unroll
    for (int dl = 0; dl < 4; ++dl) {
        float v = nsqD[dl];
        v += __shfl_xor(v, 16); v += __shfl_xor(v, 32);
        if (kc == 0)
            Np[(size_t)zh * 65536 + (size_t)(lg * 16 + n) * 512 + d0 + w * 4 + dl] = v;
    }
#pragma unroll
    for (int li = 0; li < 4; ++li) {
        int lgl = lg * 16 + w * 4 + li;
#pragma unroll
        for (int i = 0; i < 4; ++i)
            Rp[(size_t)zh * 1048576 +
               ((size_t)(kc * 4 + i) * 128 + lgl) * 512 + d0 + n] = aO[li][i];
    }
}

// ---------------------------------------------------------------------------
__global__ __launch_bounds__(128) void final_combine(
    const float* __restrict__ Rp, const float* __restrict__ Np,
    float* __restrict__ out)
{
    int rid = blockIdx.x;              // b*128 + l
    int l = rid & 127;
    int t = threadIdx.x;
    f32x4 r = { 0.f, 0.f, 0.f, 0.f };
    f32x4 nn = { 0.f, 0.f, 0.f, 0.f };
#pragma unroll
    for (int zh = 0; zh < 4; ++zh) {
        f32x4 rz = *(const f32x4*)(Rp + (size_t)zh * 1048576 + (size_t)rid * 512 + t * 4);
        f32x4 nz = *(const f32x4*)(Np + (size_t)zh * 65536 + (size_t)l * 512 + t * 4);
#pragma unroll
        for (int j = 0; j < 4; ++j) { r[j] += rz[j]; nn[j] += nz[j]; }
    }
    f32x4 y;
#pragma unroll
    for (int j = 0; j < 4; ++j) {
        float rr = 1.f / fmaxf(sqrtf(fmaxf(nn[j], 0.f)), 1e-12f);
        y[j] = r[j] * rr;
    }
    float s = y[0] * y[0] + y[1] * y[1] + y[2] * y[2] + y[3] * y[3];
#pragma unroll
    for (int off = 32; off > 0; off >>= 1) s += __shfl_down(s, off);
    __shared__ float sred[2];
    if ((t & 63) == 0) sred[t >> 6] = s;
    __syncthreads();
    float rr = 1.f / fmaxf(sqrtf(sred[0] + sred[1]), 1e-12f);
    f32x4 o = { y[0] * rr, y[1] * rr, y[2] * rr, y[3] * rr };
    *(f32x4*)(out + (size_t)rid * 512 + t * 4) = o;
}

// ===========================================================================
// SLOW FALLBACK (round-2 kernels, proven) — used when ws_size < WS_FAST
// ===========================================================================
__global__ __launch_bounds__(256) void up_kernel(
    const float* __restrict__ x,
    const float* __restrict__ wg, const float* __restrict__ wu,
    const float* __restrict__ tc1, const float* __restrict__ tc2,
    const float* __restrict__ usp, const float* __restrict__ vsp,
    _Float16* __restrict__ Hp)
{
    int lg = blockIdx.x >> 6;
    int f0 = (blockIdx.x & 63) * 16;
    int tid = threadIdx.x;
    int w = tid >> 6, lane = tid & 63;
    int n = lane & 15, kc = lane >> 4;

    __shared__ __align__(16) _Float16 Xt[256 * 40];
    __shared__ __align__(16) _Float16 Bh[32 * 16 * 24];
    __shared__ __align__(16) _Float16 Wt[16 * 528];
    __shared__ float CN[2 * 16 * 16];

    if (tid < 32) {
        int s = tid >> 4, ll = tid & 15;
        const float* row = (s ? tc2 : tc1) + (size_t)(lg * 16 + ll) * 16;
        float e[16], m = -1e30f, sum = 0.f;
#pragma unroll
        for (int k = 0; k < 16; ++k) m = fmaxf(m, row[k]);
#pragma unroll
        for (int k = 0; k < 16; ++k) { e[k] = __expf(row[k] - m); sum += e[k]; }
        float r = 1.f / sum;
#pragma unroll
        for (int k = 0; k < 16; ++k) CN[s * 256 + ll * 16 + k] = e[k] * r;
    }
    __syncthreads();

    half8 cf1 = { 0, 0, 0, 0, 0, 0, 0, 0 };
    half8 cf2 = { 0, 0, 0, 0, 0, 0, 0, 0 };
    if (kc < 2) {
#pragma unroll
        for (int j = 0; j < 8; ++j) {
            cf1[j] = (_Float16)CN[0 * 256 + n * 16 + kc * 8 + j];
            cf2[j] = (_Float16)CN[1 * 256 + n * 16 + kc * 8 + j];
        }
    }

    f32x4 zf = { 0.f, 0.f, 0.f, 0.f };
    f32x4 aU[4], aV[4];
#pragma unroll
    for (int i = 0; i < 4; ++i) { aU[i] = zf; aV[i] = zf; }
    float nsqU[4] = { 0.f, 0.f, 0.f, 0.f };
    float nsqV[4] = { 0.f, 0.f, 0.f, 0.f };

    for (int it = 0; it < 16; ++it) {
        int d0 = it * 32;
#pragma unroll
        for (int p = 0; p < 8; ++p) {
            int r = p * 32 + (tid >> 3);
            int fj = tid & 7;
            int ll = r >> 4, b = r & 15;
            f32x4 v = *(const f32x4*)(
                x + ((size_t)(b * 128 + lg * 16 + ll) * 512 + d0 + fj * 4));
            half4 h = { (_Float16)v[0], (_Float16)v[1],
                        (_Float16)v[2], (_Float16)v[3] };
            *(half4*)(&Xt[r * 40 + fj * 4]) = h;
        }
#pragma unroll
        for (int p = 0; p < 8; ++p) {
            int idx = p * 256 + tid;
            int q = idx & 3, dd = (idx >> 2) & 31, k = idx >> 7;
            f32x4 v = *(const f32x4*)(
                wg + ((size_t)k * 512 + d0 + dd) * 1024 + f0 + q * 4);
#pragma unroll
            for (int j = 0; j < 4; ++j)
                Bh[(dd * 16 + q * 4 + j) * 24 + k] = (_Float16)v[j];
        }
        __syncthreads();
#pragma unroll
        for (int fl = 0; fl < 4; ++fl) {
            int f_l = w * 4 + fl;
#pragma unroll
            for (int dg = 0; dg < 2; ++dg) {
                half8 a = { 0, 0, 0, 0, 0, 0, 0, 0 };
                if (kc < 2)
                    a = *(const half8*)(&Bh[((dg * 16 + n) * 16 + f_l) * 24 + kc * 8]);
                f32x4 cw = MFMA_F16(a, cf1, zf, 0, 0, 0);
                nsqU[fl] += cw[0] * cw[0] + cw[1] * cw[1]
                          + cw[2] * cw[2] + cw[3] * cw[3];
                half4 h4 = { (_Float16)cw[0], (_Float16)cw[1],
                             (_Float16)cw[2], (_Float16)cw[3] };
                *(half4*)(&Wt[n * 528 + f_l * 32 + dg * 16 + kc * 4]) = h4;
            }
        }
        __syncthreads();
#pragma unroll
        for (int li = 0; li < 4; ++li) {
            int l = w * 4 + li;
            half8 xf = *(const half8*)(&Xt[(l * 16 + n) * 40 + kc * 8]);
            half8 wf = *(const half8*)(&Wt[l * 528 + n * 32 + kc * 8]);
            aU[li] = MFMA_F16(xf, wf, aU[li], 0, 0, 0);
        }
#pragma unroll
        for (int p = 0; p < 8; ++p) {
            int idx = p * 256 + tid;
            int q = idx & 3, dd = (idx >> 2) & 31, k = idx >> 7;
            f32x4 v = *(const f32x4*)(
                wu + ((size_t)k * 512 + d0 + dd) * 1024 + f0 + q * 4);
#pragma unroll
            for (int j = 0; j < 4; ++j)
                Bh[(dd * 16 + q * 4 + j) * 24 + k] = (_Float16)v[j];
        }
        __syncthreads();
#pragma unroll
        for (int fl = 0; fl < 4; ++fl) {
            int f_l = w * 4 + fl;
#pragma unroll
            for (int dg = 0; dg < 2; ++dg) {
                half8 a = { 0, 0, 0, 0, 0, 0, 0, 0 };
                if (kc < 2)
                    a = *(const half8*)(&Bh[((dg * 16 + n) * 16 + f_l) * 24 + kc * 8]);
                f32x4 cw = MFMA_F16(a, cf2, zf, 0, 0, 0);
                nsqV[fl] += cw[0] * cw[0] + cw[1] * cw[1]
                          + cw[2] * cw[2] + cw[3] * cw[3];
                half4 h4 = { (_Float16)cw[0], (_Float16)cw[1],
                             (_Float16)cw[2], (_Float16)cw[3] };
                *(half4*)(&Wt[n * 528 + f_l * 32 + dg * 16 + kc * 4]) = h4;
            }
        }
        __syncthreads();
#pragma unroll
        for (int li = 0; li < 4; ++li) {
            int l = w * 4 + li;
            half8 xf = *(const half8*)(&Xt[(l * 16 + n) * 40 + kc * 8]);
            half8 wf = *(const half8*)(&Wt[l * 528 + n * 32 + kc * 8]);
            aV[li] = MFMA_F16(xf, wf, aV[li], 0, 0, 0);
        }
        __syncthreads();
    }

#pragma unroll
    for (int fl = 0; fl < 4; ++fl) {
        float vU = nsqU[fl], vV = nsqV[fl];
        vU += __shfl_xor(vU, 16); vU += __shfl_xor(vU, 32);
        vV += __shfl_xor(vV, 16); vV += __shfl_xor(vV, 32);
        if (kc == 0) {
            CN[0 * 256 + n * 16 + w * 4 + fl] = vU;
            CN[1 * 256 + n * 16 + w * 4 + fl] = vV;
        }
    }
    __syncthreads();

    int f = f0 + n;
    float usv = fabsf(usp[f]);
    float vsv = fabsf(vsp[f]) * 22.627416997969522f;
#pragma unroll
    for (int li = 0; li < 4; ++li) {
        int lgl = lg * 16 + w * 4 + li;
        float r1 = 1.f / fmaxf(sqrtf(CN[0 * 256 + (w * 4 + li) * 16 + n]), 1e-12f);
        float r2 = 1.f / fmaxf(sqrtf(CN[1 * 256 + (w * 4 + li) * 16 + n]), 1e-12f);
#pragma unroll
        for (int i = 0; i < 4; ++i) {
            float u = aU[li][i] * r1;
            float v = aV[li][i] * r2;
            float zz = vsv * v;
            float sil = zz / (1.f + __expf(-zz));
            float h = sil * (usv * u);
            Hp[((size_t)lgl * 16 + kc * 4 + i) * 1024 + f] = (_Float16)h;
        }
    }
}

__global__ __launch_bounds__(256) void down_kernel(
    const float* __restrict__ wd, const float* __restrict__ tc3,
    const _Float16* __restrict__ Hp, float* __restrict__ out)
{
    int lg = blockIdx.x >> 5;
    int d0 = (blockIdx.x & 31) * 16;
    int tid = threadIdx.x;
    int w = tid >> 6, lane = tid & 63;
    int n = lane & 15, kc = lane >> 4;

    __shared__ __align__(16) _Float16 Ht[256 * 40];
    __shared__ __align__(16) _Float16 Bh[32 * 16 * 24];
    __shared__ __align__(16) _Float16 Wt[16 * 528];
    __shared__ float CN[16 * 16];

    if (tid < 16) {
        const float* row = tc3 + (size_t)(lg * 16 + tid) * 16;
        float e[16], m = -1e30f, sum = 0.f;
#pragma unroll
        for (int k = 0; k < 16; ++k) m = fmaxf(m, row[k]);
#pragma unroll
        for (int k = 0; k < 16; ++k) { e[k] = __expf(row[k] - m); sum += e[k]; }
        float r = 1.f / sum;
#pragma unroll
        for (int k = 0; k < 16; ++k) CN[tid * 16 + k] = e[k] * r;
    }
    __syncthreads();

    half8 cf3 = { 0, 0, 0, 0, 0, 0, 0, 0 };
    if (kc < 2) {
#pragma unroll
        for (int j = 0; j < 8; ++j)
            cf3[j] = (_Float16)CN[n * 16 + kc * 8 + j];
    }

    f32x4 zf = { 0.f, 0.f, 0.f, 0.f };
    f32x4 aO[4];
#pragma unroll
    for (int i = 0; i < 4; ++i) aO[i] = zf;
    float nsqD[4] = { 0.f, 0.f, 0.f, 0.f };

    for (int it = 0; it < 32; ++it) {
        int f0 = it * 32;
#pragma unroll
        for (int p = 0; p < 8; ++p) {
            int r = p * 32 + (tid >> 3);
            int hj = tid & 7;
            int ll = r >> 4, b = r & 15;
            half4 v = *(const half4*)(
                Hp + ((size_t)(lg * 16 + ll) * 16 + b) * 1024 + f0 + hj * 4);
            *(half4*)(&Ht[r * 40 + hj * 4]) = v;
        }
#pragma unroll
        for (int p = 0; p < 8; ++p) {
            int idx = p * 256 + tid;
            int q = idx & 3, ff = (idx >> 2) & 31, k = idx >> 7;
            f32x4 v = *(const f32x4*)(
                wd + ((size_t)k * 1024 + f0 + ff) * 512 + d0 + q * 4);
#pragma unroll
            for (int j = 0; j < 4; ++j)
                Bh[(ff * 16 + q * 4 + j) * 24 + k] = (_Float16)v[j];
        }
        __syncthreads();
#pragma unroll
        for (int dl = 0; dl < 4; ++dl) {
            int d_l = w * 4 + dl;
#pragma unroll
            for (int fg = 0; fg < 2; ++fg) {
                half8 a = { 0, 0, 0, 0, 0, 0, 0, 0 };
                if (kc < 2)
                    a = *(const half8*)(&Bh[((fg * 16 + n) * 16 + d_l) * 24 + kc * 8]);
                f32x4 cw = MFMA_F16(a, cf3, zf, 0, 0, 0);
                nsqD[dl] += cw[0] * cw[0] + cw[1] * cw[1]
                          + cw[2] * cw[2] + cw[3] * cw[3];
                half4 h4 = { (_Float16)cw[0], (_Float16)cw[1],
                             (_Float16)cw[2], (_Float16)cw[3] };
                *(half4*)(&Wt[n * 528 + d_l * 32 + fg * 16 + kc * 4]) = h4;
            }
        }
        __syncthreads();
#pragma unroll
        for (int li = 0; li < 4; ++li) {
            int l = w * 4 + li;
            half8 hf = *(const half8*)(&Ht[(l * 16 + n) * 40 + kc * 8]);
            half8 wf = *(const half8*)(&Wt[l * 528 + n * 32 + kc * 8]);
            aO[li] = MFMA_F16(hf, wf, aO[li], 0, 0, 0);
        }
        __syncthreads();
    }

#pragma unroll
    for (int dl = 0; dl < 4; ++dl) {
        float v = nsqD[dl];
        v += __shfl_xor(v, 16); v += __shfl_xor(v, 32);
        if (kc == 0) CN[n * 16 + w * 4 + dl] = v;
    }
    __syncthreads();

#pragma unroll
    for (int li = 0; li < 4; ++li) {
        int lgl = lg * 16 + w * 4 + li;
        float r3 = 1.f / fmaxf(sqrtf(CN[(w * 4 + li) * 16 + n]), 1e-12f);
#pragma unroll
        for (int i = 0; i < 4; ++i)
            out[((size_t)(kc * 4 + i) * 128 + lgl) * 512 + d0 + n] = aO[li][i] * r3;
    }
}

__global__ __launch_bounds__(128) void final_kernel(float* __restrict__ out)
{
    int rid = blockIdx.x;
    int t = threadIdx.x;
    f32x4 y = *(const f32x4*)(out + (size_t)rid * 512 + t * 4);
    float s = y[0] * y[0] + y[1] * y[1] + y[2] * y[2] + y[3] * y[3];
#pragma unroll
    for (int off = 32; off > 0; off >>= 1) s += __shfl_down(s, off);
    __shared__ float sred[2];
    if ((t & 63) == 0) sred[t >> 6] = s;
    __syncthreads();
    float rr = 1.f / fmaxf(sqrtf(sred[0] + sred[1]), 1e-12f);
    f32x4 o = { y[0] * rr, y[1] * rr, y[2] * rr, y[3] * rr };
    *(f32x4*)(out + (size_t)rid * 512 + t * 4) = o;
}

// ---------------------------------------------------------------------------
extern "C" void kernel_launch(void* const* d_in, const int* in_sizes, int n_in,
                              void* d_out, int out_size, void* d_ws, size_t ws_size,
                              hipStream_t stream)
{
    (void)in_sizes; (void)n_in; (void)out_size;
    const float* x   = (const float*)d_in[0];
    const float* wg  = (const float*)d_in[1];
    const float* wu  = (const float*)d_in[2];
    const float* wd  = (const float*)d_in[3];
    const float* tc1 = (const float*)d_in[4];
    const float* tc2 = (const float*)d_in[5];
    const float* tc3 = (const float*)d_in[6];
    const float* usp = (const float*)d_in[7];
    const float* vsp = (const float*)d_in[8];
    float* outp = (float*)d_out;
    char* ws = (char*)d_ws;

    if (ws_size >= WS_FAST) {
        _Float16* P1  = (_Float16*)(ws + OFF_P1);
        _Float16* P2  = (_Float16*)(ws + OFF_P2);
        _Float16* P3n = (_Float16*)(ws + OFF_P3n);  // 17..33 MiB (after Np)
        _Float16* XA  = (_Float16*)(ws + OFF_XA);   // 32..34 MiB
        _Float16* U2  = (_Float16*)(ws + OFF_U2);   // 34..38 MiB
        _Float16* S   = (_Float16*)(ws + OFF_S);    // 38..42 MiB
        float* Rp = (float*)(ws + OFF_P1);   // overlays P1 (dead after up)
        float* Np = (float*)(ws + OFF_P2);   // 16..17 MiB (P2 dead after up)
        prep_pre<<<dim3(1280), dim3(256), 0, stream>>>(x, wg, wu, P1, P2, XA);
        up_split<<<dim3(1024), dim3(256), 0, stream>>>(P1, P2, XA, tc1, tc2,
                                                       usp, vsp, U2, S);
        prep_basis_all<<<dim3(512, 1), dim3(256), 0, stream>>>(
            wg, wu, wd, P1, P2, P3n, 2);                   // P3 at 17 MiB
        down_fast<<<dim3(1024), dim3(256), 0, stream>>>(P3n, tc3, S, U2, Rp, Np);
        final_combine<<<dim3(2048), dim3(128), 0, stream>>>(Rp, Np, outp);
    } else {
        _Float16* Hp = (_Float16*)ws;
        up_kernel<<<dim3(512), dim3(256), 0, stream>>>(x, wg, wu, tc1, tc2,
                                                       usp, vsp, Hp);
        down_kernel<<<dim3(256), dim3(256), 0, stream>>>(wd, tc3, Hp, outp);
        final_kernel<<<dim3(2048), dim3(128), 0, stream>>>(outp);
    }
}